// Round 5
// baseline (361.991 us; speedup 1.0000x reference)
//
#include <hip/hip_runtime.h>

#define D 128
#define NN 512
#define BB 512

typedef __attribute__((ext_vector_type(8))) short short8;
typedef __attribute__((ext_vector_type(4))) float f32x4;

__device__ __forceinline__ unsigned int fbits(float f) {
  union { float f; unsigned int u; } v; v.f = f; return v.u;
}
__device__ __forceinline__ float ubits(unsigned int u) {
  union { unsigned int u; float f; } v; v.u = u; return v.f;
}
__device__ __forceinline__ unsigned short f2bf(float f) {
  unsigned int x = fbits(f);
  return (unsigned short)((x + 0x7fffu + ((x >> 16) & 1u)) >> 16);
}
__device__ __forceinline__ float h2f(unsigned short u) {
  _Float16 h; __builtin_memcpy(&h, &u, 2); return (float)h;
}
__device__ __forceinline__ unsigned short f2h(float f) {
  _Float16 h = (_Float16)f; unsigned short u; __builtin_memcpy(&u, &h, 2); return u;
}
__device__ __forceinline__ float lrelu(float x) { return x > 0.f ? x : 0.01f * x; }

// MFMA fragment-order index for W[k][n] (16x16x32, B-operand, 8 n-tiles x 4 k-tiles):
// chunk = ((n>>4)*4 + (k>>5))*64 + ((k>>3)&3)*16 + (n&15); flat = chunk*8 + (k&7)
// n-chunks 0-3 -> chunks 0-15 (u16 0..8191), n-chunks 4-7 -> chunks 16-31 (8192..16383):
// each output-col half is a CONTIGUOUS 16 KiB block.
__device__ __forceinline__ int fragidx(int k, int n) {
  return ((((n >> 4) * 4 + (k >> 5)) * 64 + ((k >> 3) & 3) * 16 + (n & 15)) << 3) + (k & 7);
}

// ---- prep: WhF/WlF = split-bf16(Wk @ Wa1) in FRAGMENT order; c3 = rel@Wa3 + b_att
__global__ __launch_bounds__(256) void prep_kernel(
    const float* __restrict__ Wk, const float* __restrict__ Watt,
    const float* __restrict__ batt, const float* __restrict__ rel,
    unsigned short* __restrict__ WhF, unsigned short* __restrict__ WlF,
    float* __restrict__ c3) {
  __shared__ float rowS[D];
  __shared__ float psum[2][D];
  const int blk = blockIdx.x;      // 0..(D+BB-1): row k of Wkk, then batch rows
  const int t = threadIdx.x;       // 256
  const float* src = (blk < D) ? (Wk + blk * D) : (rel + (blk - D) * D);
  const float* W   = (blk < D) ? Watt : (Watt + 2 * D * D);
  if (t < D) rowS[t] = src[t];
  __syncthreads();
  const int d = t & 127, half = t >> 7;
  const float* Wp = W + (half * 64) * D + d;
  float a = 0.f;
  #pragma unroll 8
  for (int k = 0; k < 64; ++k) a += rowS[half * 64 + k] * Wp[k * D];
  psum[half][d] = a;
  __syncthreads();
  if (t < D) {
    const float w = psum[0][t] + psum[1][t];
    if (blk < D) {
      const unsigned int ub = fbits(w);
      const int idx = fragidx(blk, t);        // k = blk, n = t
      WhF[idx] = (unsigned short)(ub >> 16);
      WlF[idx] = f2bf(w - ubits(ub & 0xFFFF0000u));
    } else {
      c3[(blk - D) * D + t] = w + batt[t];
    }
  }
}

// ---- g1 = (key*mask) @ Wkk via split-bf16 MFMA (fp32-accurate), stored fp16 ----
// Split-N: even blocks produce cols 0-63, odd blocks cols 64-127. LDS = 32 KiB
// (one contiguous fragment half per matrix) -> 4-5 blocks/CU. Key converted
// per-kt (short frag liveness -> low VGPR). Unconditional key loads + cndmask
// zeroing (no mask->load dependency); masked rows skip the g1h store.
// Block pair (2j,2j+1) reads the same key rows concurrently -> L3 temporal hit.
__global__ __launch_bounds__(256) void gemm_g1_kernel(
    const float* __restrict__ key, const int* __restrict__ mask,
    const unsigned short* __restrict__ WhF, const unsigned short* __restrict__ WlF,
    unsigned short* __restrict__ g1h) {
  __shared__ __align__(16) unsigned short whlds[8192];
  __shared__ __align__(16) unsigned short wllds[8192];
  const int t = threadIdx.x;
  const int ch = blockIdx.x & 1;               // output-col half
  const unsigned short* Wh = WhF + ch * 8192;
  const unsigned short* Wl = WlF + ch * 8192;
  #pragma unroll
  for (int i = 0; i < 4; ++i) {
    const int unit = t + i * 256;              // 16B units 0..1023
    *reinterpret_cast<uint4*>(&whlds[unit * 8]) = *reinterpret_cast<const uint4*>(Wh + unit * 8);
    *reinterpret_cast<uint4*>(&wllds[unit * 8]) = *reinterpret_cast<const uint4*>(Wl + unit * 8);
  }
  __syncthreads();
  const int wave = t >> 6, lane = t & 63;
  const int q = lane >> 4, l15 = lane & 15;
  const int nrt = (BB * NN) / 64;              // 4096 row-tiles
  const int rstride = gridDim.x >> 1;
  for (int rt = blockIdx.x >> 1; rt < nrt; rt += rstride) {
    const long rowbase = (long)rt * 64 + wave * 16;
    const long r = rowbase + l15;
    const int mk = mask[r];
    f32x4 acc[4];
    #pragma unroll
    for (int c = 0; c < 4; ++c) acc[c] = (f32x4){0.f, 0.f, 0.f, 0.f};
    #pragma unroll
    for (int kt = 0; kt < 4; ++kt) {
      const float* kp = key + r * D + kt * 32 + q * 8;
      float xs[8];
      *reinterpret_cast<float4*>(&xs[0]) = *reinterpret_cast<const float4*>(kp);
      *reinterpret_cast<float4*>(&xs[4]) = *reinterpret_cast<const float4*>(kp + 4);
      union { unsigned int u[4]; short8 v; } cvh, cvl;
      #pragma unroll
      for (int p2 = 0; p2 < 4; ++p2) {
        float a = xs[2 * p2], b = xs[2 * p2 + 1];
        if (!mk) { a = 0.f; b = 0.f; }
        const unsigned int ua = fbits(a), ub = fbits(b);
        cvh.u[p2] = (ua >> 16) | (ub & 0xFFFF0000u);
        const float ra = a - ubits(ua & 0xFFFF0000u);
        const float rb = b - ubits(ub & 0xFFFF0000u);
        cvl.u[p2] = (unsigned int)f2bf(ra) | ((unsigned int)f2bf(rb) << 16);
      }
      const short8 ah = cvh.v, al = cvl.v;
      #pragma unroll
      for (int c = 0; c < 4; ++c) {
        const short8 bh = *reinterpret_cast<const short8*>(&whlds[((c * 4 + kt) * 64 + lane) * 8]);
        const short8 bl = *reinterpret_cast<const short8*>(&wllds[((c * 4 + kt) * 64 + lane) * 8]);
        acc[c] = __builtin_amdgcn_mfma_f32_16x16x32_bf16(ah, bh, acc[c], 0, 0, 0);
        acc[c] = __builtin_amdgcn_mfma_f32_16x16x32_bf16(al, bh, acc[c], 0, 0, 0);
        acc[c] = __builtin_amdgcn_mfma_f32_16x16x32_bf16(ah, bl, acc[c], 0, 0, 0);
      }
    }
    // C/D layout: col(n) = ch*64 + c*16 + (lane&15), row(m) = rowbase + (lane>>4)*4 + reg
    const int4 mr4 = *reinterpret_cast<const int4*>(mask + rowbase + q * 4);
    const int mrr[4] = {mr4.x, mr4.y, mr4.z, mr4.w};
    #pragma unroll
    for (int c = 0; c < 4; ++c) {
      #pragma unroll
      for (int reg = 0; reg < 4; ++reg) {
        if (mrr[reg]) {
          const long row = rowbase + q * 4 + reg;
          g1h[row * D + ch * 64 + c * 16 + l15] = f2h(acc[c][reg]);
        }
      }
    }
  }
}

// ---- fused 3-hop kernel: one block (512 thr) per batch row ---------------------
// Mask-compacted (idxS, padded to x128). NEW: each thread's phase-4 V slice for
// the first 256 compacted rows (typical: all of them) is loaded ONCE into 64
// fp32 VGPRs before the hop loop (latency hidden under hop-0 phases 1-3);
// phase 4 is register-resident for ii<2, load-path for ii>=2. Accumulation
// order identical to the load version -> bit-exact output.
__global__ __launch_bounds__(512, 2) void hops_kernel(
    const float* __restrict__ e1, const int* __restrict__ mask,
    const float* __restrict__ value, const unsigned short* __restrict__ g1h,
    const float* __restrict__ Wlin, const float* __restrict__ blin,
    const float* __restrict__ Watt, const float* __restrict__ Wv,
    const float* __restrict__ c3, float* __restrict__ out) {
  __shared__ float uS[D], cS[D], ubS[D], opS[D];
  __shared__ float attS[NN];
  __shared__ float part[4][D];
  __shared__ float oscr[8][D];
  __shared__ float redA[8], redB[8];
  __shared__ int idxS[NN];
  __shared__ int redI[8];
  __shared__ int padRowS;
  const int b = blockIdx.x;
  const int t = threadIdx.x;
  const int wv = t >> 6, lane = t & 63;
  const int grp = t >> 4, l = t & 15, d0 = (t & 15) * 8;
  const long base = (long)b * NN * D;
  const int* mb = mask + b * NN;
  if (t < D) uS[t] = e1[b * D + t];
  // ---- compaction: list of unmasked row indices (order-preserving) ----
  const int myMask = mb[t];
  {
    const unsigned long long bal = __ballot(myMask != 0);
    const int lanePre = __popcll(bal & ((1ULL << lane) - 1ULL));
    if (lane == 0) redI[wv] = __popcll(bal);
    if (!myMask) padRowS = t;          // benign race: any masked row works
    __syncthreads();
    int wbase = 0, cnt = 0;
    #pragma unroll
    for (int w2 = 0; w2 < 8; ++w2) {
      const int c = redI[w2];
      if (w2 < wv) wbase += c;
      cnt += c;
    }
    if (myMask) idxS[wbase + lanePre] = t;
    const int cntPad = (cnt + 127) & ~127;
    __syncthreads();
    for (int i = cnt + t; i < cntPad; i += 512) idxS[i] = padRowS;
    redI[0] = cntPad >> 7;             // number of 128-row blocks (uniform rewrite)
    __syncthreads();
  }
  const int nb = redI[0];
  // ---- persistent V prefetch: first 2 index blocks (8 rows x 8 f32 = 64 VGPR).
  // Statically indexed throughout (rule: no runtime-indexed register arrays).
  float4 va0[4], vb0[4], va1[4], vb1[4];
  if (nb > 0) {
    #pragma unroll
    for (int j2 = 0; j2 < 4; ++j2) {
      const int n = idxS[j2 * 32 + grp];
      const float* vp = value + base + (long)n * D + d0;
      va0[j2] = *reinterpret_cast<const float4*>(vp);
      vb0[j2] = *reinterpret_cast<const float4*>(vp + 4);
    }
  }
  if (nb > 1) {
    #pragma unroll
    for (int j2 = 0; j2 < 4; ++j2) {
      const int n = idxS[128 + j2 * 32 + grp];
      const float* vp = value + base + (long)n * D + d0;
      va1[j2] = *reinterpret_cast<const float4*>(vp);
      vb1[j2] = *reinterpret_cast<const float4*>(vp + 4);
    }
  }
  for (int hop = 0; hop < 3; ++hop) {
    // phase 1: 4 roles x 128 threads: role0/1 = c halves, role2/3 = ub halves
    {
      const int d = t & 127, role = t >> 7;
      const float* W = (role < 2) ? (Watt + D * D) : Wlin;
      const int k0 = (role & 1) * 64;
      const float* Wp = W + k0 * D + d;
      float a = 0.f;
      #pragma unroll 8
      for (int k = 0; k < 64; ++k) a += uS[k0 + k] * Wp[k * D];
      part[role][d] = a;
    }
    __syncthreads();
    if (t < D) cS[t] = part[0][t] + part[1][t] + c3[b * D + t];
    else if (t < 2 * D) { const int d = t - D; ubS[d] = lrelu(part[2][d] + part[3][d] + blin[d]); }
    __syncthreads();
    // waves 0-1: masked-row att value partials -> redB[0], redB[1]
    // (read in phase 3 BEFORE any phase-3 write to redB; separated by barrier)
    if (t < 128) {
      float v = lrelu(cS[t]);
      #pragma unroll
      for (int off = 32; off > 0; off >>= 1) v += __shfl_xor(v, off, 64);
      if (lane == 0) redB[wv] = v;
    }
    // phase 2: att[n] = sum_d lrelu(g1[n,d] + c[d]) for UNMASKED rows only
    {
      float creg[8];
      #pragma unroll
      for (int j = 0; j < 8; ++j) creg[j] = cS[d0 + j];
      for (int ii = 0; ii < nb; ++ii) {
        int ns[4]; uint4 g[4];
        #pragma unroll
        for (int j2 = 0; j2 < 4; ++j2) ns[j2] = idxS[ii * 128 + j2 * 32 + grp];
        #pragma unroll
        for (int j2 = 0; j2 < 4; ++j2)
          g[j2] = *reinterpret_cast<const uint4*>(g1h + base + (long)ns[j2] * D + d0);
        #pragma unroll
        for (int j2 = 0; j2 < 4; ++j2) {
          const unsigned short* e = reinterpret_cast<const unsigned short*>(&g[j2]);
          float s = 0.f;
          #pragma unroll
          for (int j = 0; j < 8; ++j) s += lrelu(h2f(e[j]) + creg[j]);
          #pragma unroll
          for (int off = 8; off > 0; off >>= 1) s += __shfl_xor(s, off, 16);
          if (l == 0) attS[ns[j2]] = s;
        }
      }
    }
    __syncthreads();
    // phase 3: masked softmax (max over ALL n incl. masked — matches ref); n = t
    {
      const float av = myMask ? attS[t] : (redB[0] + redB[1]);
      float m = av;
      #pragma unroll
      for (int off = 32; off > 0; off >>= 1) m = fmaxf(m, __shfl_xor(m, off, 64));
      if (lane == 0) redA[wv] = m;
      __syncthreads();
      m = redA[0];
      #pragma unroll
      for (int w2 = 1; w2 < 8; ++w2) m = fmaxf(m, redA[w2]);
      const float e0 = __expf(av - m) * (myMask ? 1.f : 0.f);
      float ss = e0;
      #pragma unroll
      for (int off = 32; off > 0; off >>= 1) ss += __shfl_xor(ss, off, 64);
      if (lane == 0) redB[wv] = ss;
      __syncthreads();
      float s = 1e-5f;
      #pragma unroll
      for (int w2 = 0; w2 < 8; ++w2) s += redB[w2];
      attS[t] = e0 / s;
    }
    __syncthreads();
    // phase 4: o_pre[d] = sum_n p[n] * value[n,d], unmasked rows only (p==0 else)
    // ii=0,1 from persistent registers; ii>=2 via loads. Same accumulation order
    // as the all-loads version -> bit-identical.
    {
      float acc8[8];
      #pragma unroll
      for (int j = 0; j < 8; ++j) acc8[j] = 0.f;
      if (nb > 0) {
        #pragma unroll
        for (int j2 = 0; j2 < 4; ++j2) {
          const float p = attS[idxS[j2 * 32 + grp]];
          acc8[0] += p * va0[j2].x; acc8[1] += p * va0[j2].y;
          acc8[2] += p * va0[j2].z; acc8[3] += p * va0[j2].w;
          acc8[4] += p * vb0[j2].x; acc8[5] += p * vb0[j2].y;
          acc8[6] += p * vb0[j2].z; acc8[7] += p * vb0[j2].w;
        }
      }
      if (nb > 1) {
        #pragma unroll
        for (int j2 = 0; j2 < 4; ++j2) {
          const float p = attS[idxS[128 + j2 * 32 + grp]];
          acc8[0] += p * va1[j2].x; acc8[1] += p * va1[j2].y;
          acc8[2] += p * va1[j2].z; acc8[3] += p * va1[j2].w;
          acc8[4] += p * vb1[j2].x; acc8[5] += p * vb1[j2].y;
          acc8[6] += p * vb1[j2].z; acc8[7] += p * vb1[j2].w;
        }
      }
      for (int ii = 2; ii < nb; ++ii) {
        int ns[4]; float4 va[4], vb[4];
        #pragma unroll
        for (int j2 = 0; j2 < 4; ++j2) ns[j2] = idxS[ii * 128 + j2 * 32 + grp];
        #pragma unroll
        for (int j2 = 0; j2 < 4; ++j2) {
          const float* vp = value + base + (long)ns[j2] * D + d0;
          va[j2] = *reinterpret_cast<const float4*>(vp);
          vb[j2] = *reinterpret_cast<const float4*>(vp + 4);
        }
        #pragma unroll
        for (int j2 = 0; j2 < 4; ++j2) {
          const float p = attS[ns[j2]];
          acc8[0] += p * va[j2].x; acc8[1] += p * va[j2].y;
          acc8[2] += p * va[j2].z; acc8[3] += p * va[j2].w;
          acc8[4] += p * vb[j2].x; acc8[5] += p * vb[j2].y;
          acc8[6] += p * vb[j2].z; acc8[7] += p * vb[j2].w;
        }
      }
      #pragma unroll
      for (int j = 0; j < 8; ++j) {
        acc8[j] += __shfl_xor(acc8[j], 16, 64);
        acc8[j] += __shfl_xor(acc8[j], 32, 64);
      }
      if (lane < 16) {
        #pragma unroll
        for (int j = 0; j < 8; ++j) oscr[wv][lane * 8 + j] = acc8[j];
      }
    }
    __syncthreads();
    if (t < D) {
      float s = 0.f;
      #pragma unroll
      for (int w2 = 0; w2 < 8; ++w2) s += oscr[w2][t];
      opS[t] = s;
    }
    __syncthreads();
    // phase 5a: o = o_pre @ Wv, 4-way k-split
    {
      const int d = t & 127, role = t >> 7;
      const int k0 = role * 32;
      const float* Wp = Wv + k0 * D + d;
      float a = 0.f;
      #pragma unroll 8
      for (int k = 0; k < 32; ++k) a += opS[k0 + k] * Wp[k * D];
      part[role][d] = a;
    }
    __syncthreads();
    // phase 5b: u = l2norm(ub + o)
    {
      float un = 0.f, sq = 0.f;
      if (t < D) {
        un = ubS[t] + part[0][t] + part[1][t] + part[2][t] + part[3][t];
        sq = un * un;
      }
      #pragma unroll
      for (int off = 32; off > 0; off >>= 1) sq += __shfl_xor(sq, off, 64);
      if (lane == 0) redA[wv] = sq;
      __syncthreads();
      float ns = 0.f;
      #pragma unroll
      for (int w2 = 0; w2 < 8; ++w2) ns += redA[w2];
      const float norm = sqrtf(ns);
      const float inv = (norm > 1e-12f) ? (1.f / norm) : 1e12f;
      if (t < D) uS[t] = un * inv;
    }
    __syncthreads();
  }
  if (t < D) out[b * D + t] = uS[t];
}

extern "C" void kernel_launch(void* const* d_in, const int* in_sizes, int n_in,
                              void* d_out, int out_size, void* d_ws, size_t ws_size,
                              hipStream_t stream) {
  const float* e1   = (const float*)d_in[0];
  const float* rel  = (const float*)d_in[1];
  const float* key  = (const float*)d_in[2];
  const float* val  = (const float*)d_in[3];
  const int*   mask = (const int*)d_in[4];
  const float* Wk   = (const float*)d_in[5];
  const float* Wv   = (const float*)d_in[6];
  const float* Wlin = (const float*)d_in[7];
  const float* blin = (const float*)d_in[8];
  const float* Watt = (const float*)d_in[9];
  const float* batt = (const float*)d_in[10];
  float* out = (float*)d_out;

  char* ws = (char*)d_ws;
  unsigned short* WhF = (unsigned short*)ws;                   // 32 KB (fragment order)
  unsigned short* WlF = (unsigned short*)(ws + 32 * 1024);     // 32 KB (fragment order)
  float*          c3  = (float*)(ws + 64 * 1024);              // 256 KB
  unsigned short* g1h = (unsigned short*)(ws + 512 * 1024);    // 64 MiB fp16

  prep_kernel<<<D + BB, 256, 0, stream>>>(Wk, Watt, batt, rel, WhF, WlF, c3);
  gemm_g1_kernel<<<2048, 256, 0, stream>>>(key, mask, WhF, WlF, g1h);
  hops_kernel<<<BB, 512, 0, stream>>>(e1, mask, val, g1h, Wlin, blin, Watt, Wv, c3, out);
}

// Round 6
// 352.861 us; speedup vs baseline: 1.0259x; 1.0259x over previous
//
#include <hip/hip_runtime.h>

#define D 128
#define NN 512
#define BB 512

typedef __attribute__((ext_vector_type(8))) short short8;
typedef __attribute__((ext_vector_type(4))) float f32x4;

__device__ __forceinline__ unsigned int fbits(float f) {
  union { float f; unsigned int u; } v; v.f = f; return v.u;
}
__device__ __forceinline__ float ubits(unsigned int u) {
  union { unsigned int u; float f; } v; v.u = u; return v.f;
}
__device__ __forceinline__ unsigned short f2bf(float f) {
  unsigned int x = fbits(f);
  return (unsigned short)((x + 0x7fffu + ((x >> 16) & 1u)) >> 16);
}
__device__ __forceinline__ float h2f(unsigned short u) {
  _Float16 h; __builtin_memcpy(&h, &u, 2); return (float)h;
}
__device__ __forceinline__ unsigned short f2h(float f) {
  _Float16 h = (_Float16)f; unsigned short u; __builtin_memcpy(&u, &h, 2); return u;
}
__device__ __forceinline__ float lrelu(float x) { return x > 0.f ? x : 0.01f * x; }

// MFMA fragment-order index for W[k][n] (16x16x32, B-operand, 8 n-tiles x 4 k-tiles):
// chunk = ((n>>4)*4 + (k>>5))*64 + ((k>>3)&3)*16 + (n&15); flat = chunk*8 + (k&7)
// n-chunks 0-3 -> chunks 0-15 (u16 0..8191), n-chunks 4-7 -> chunks 16-31 (8192..16383):
// each output-col half is a CONTIGUOUS 16 KiB block.
__device__ __forceinline__ int fragidx(int k, int n) {
  return ((((n >> 4) * 4 + (k >> 5)) * 64 + ((k >> 3) & 3) * 16 + (n & 15)) << 3) + (k & 7);
}

// ---- prep: WhF/WlF = split-bf16(Wk @ Wa1) in FRAGMENT order; c3 = rel@Wa3 + b_att
__global__ __launch_bounds__(256) void prep_kernel(
    const float* __restrict__ Wk, const float* __restrict__ Watt,
    const float* __restrict__ batt, const float* __restrict__ rel,
    unsigned short* __restrict__ WhF, unsigned short* __restrict__ WlF,
    float* __restrict__ c3) {
  __shared__ float rowS[D];
  __shared__ float psum[2][D];
  const int blk = blockIdx.x;      // 0..(D+BB-1): row k of Wkk, then batch rows
  const int t = threadIdx.x;       // 256
  const float* src = (blk < D) ? (Wk + blk * D) : (rel + (blk - D) * D);
  const float* W   = (blk < D) ? Watt : (Watt + 2 * D * D);
  if (t < D) rowS[t] = src[t];
  __syncthreads();
  const int d = t & 127, half = t >> 7;
  const float* Wp = W + (half * 64) * D + d;
  float a = 0.f;
  #pragma unroll 8
  for (int k = 0; k < 64; ++k) a += rowS[half * 64 + k] * Wp[k * D];
  psum[half][d] = a;
  __syncthreads();
  if (t < D) {
    const float w = psum[0][t] + psum[1][t];
    if (blk < D) {
      const unsigned int ub = fbits(w);
      const int idx = fragidx(blk, t);        // k = blk, n = t
      WhF[idx] = (unsigned short)(ub >> 16);
      WlF[idx] = f2bf(w - ubits(ub & 0xFFFF0000u));
    } else {
      c3[(blk - D) * D + t] = w + batt[t];
    }
  }
}

// ---- g1 = (key*mask) @ Wkk via split-bf16 MFMA (fp32-accurate), stored fp16 ----
// Split-N: even blocks produce cols 0-63, odd blocks cols 64-127. LDS = 32 KiB
// (one contiguous fragment half per matrix) -> 4-5 blocks/CU. Key converted
// per-kt (short frag liveness -> low VGPR). Unconditional key loads + cndmask
// zeroing (no mask->load dependency); masked rows skip the g1h store.
__global__ __launch_bounds__(256) void gemm_g1_kernel(
    const float* __restrict__ key, const int* __restrict__ mask,
    const unsigned short* __restrict__ WhF, const unsigned short* __restrict__ WlF,
    unsigned short* __restrict__ g1h) {
  __shared__ __align__(16) unsigned short whlds[8192];
  __shared__ __align__(16) unsigned short wllds[8192];
  const int t = threadIdx.x;
  const int ch = blockIdx.x & 1;               // output-col half
  const unsigned short* Wh = WhF + ch * 8192;
  const unsigned short* Wl = WlF + ch * 8192;
  #pragma unroll
  for (int i = 0; i < 4; ++i) {
    const int unit = t + i * 256;              // 16B units 0..1023
    *reinterpret_cast<uint4*>(&whlds[unit * 8]) = *reinterpret_cast<const uint4*>(Wh + unit * 8);
    *reinterpret_cast<uint4*>(&wllds[unit * 8]) = *reinterpret_cast<const uint4*>(Wl + unit * 8);
  }
  __syncthreads();
  const int wave = t >> 6, lane = t & 63;
  const int q = lane >> 4, l15 = lane & 15;
  const int nrt = (BB * NN) / 64;              // 4096 row-tiles
  const int rstride = gridDim.x >> 1;
  for (int rt = blockIdx.x >> 1; rt < nrt; rt += rstride) {
    const long rowbase = (long)rt * 64 + wave * 16;
    const long r = rowbase + l15;
    const int mk = mask[r];
    f32x4 acc[4];
    #pragma unroll
    for (int c = 0; c < 4; ++c) acc[c] = (f32x4){0.f, 0.f, 0.f, 0.f};
    #pragma unroll
    for (int kt = 0; kt < 4; ++kt) {
      const float* kp = key + r * D + kt * 32 + q * 8;
      float xs[8];
      *reinterpret_cast<float4*>(&xs[0]) = *reinterpret_cast<const float4*>(kp);
      *reinterpret_cast<float4*>(&xs[4]) = *reinterpret_cast<const float4*>(kp + 4);
      union { unsigned int u[4]; short8 v; } cvh, cvl;
      #pragma unroll
      for (int p2 = 0; p2 < 4; ++p2) {
        float a = xs[2 * p2], b = xs[2 * p2 + 1];
        if (!mk) { a = 0.f; b = 0.f; }
        const unsigned int ua = fbits(a), ub = fbits(b);
        cvh.u[p2] = (ua >> 16) | (ub & 0xFFFF0000u);
        const float ra = a - ubits(ua & 0xFFFF0000u);
        const float rb = b - ubits(ub & 0xFFFF0000u);
        cvl.u[p2] = (unsigned int)f2bf(ra) | ((unsigned int)f2bf(rb) << 16);
      }
      const short8 ah = cvh.v, al = cvl.v;
      #pragma unroll
      for (int c = 0; c < 4; ++c) {
        const short8 bh = *reinterpret_cast<const short8*>(&whlds[((c * 4 + kt) * 64 + lane) * 8]);
        const short8 bl = *reinterpret_cast<const short8*>(&wllds[((c * 4 + kt) * 64 + lane) * 8]);
        acc[c] = __builtin_amdgcn_mfma_f32_16x16x32_bf16(ah, bh, acc[c], 0, 0, 0);
        acc[c] = __builtin_amdgcn_mfma_f32_16x16x32_bf16(al, bh, acc[c], 0, 0, 0);
        acc[c] = __builtin_amdgcn_mfma_f32_16x16x32_bf16(ah, bl, acc[c], 0, 0, 0);
      }
    }
    // C/D layout: col(n) = ch*64 + c*16 + (lane&15), row(m) = rowbase + (lane>>4)*4 + reg
    const int4 mr4 = *reinterpret_cast<const int4*>(mask + rowbase + q * 4);
    const int mrr[4] = {mr4.x, mr4.y, mr4.z, mr4.w};
    #pragma unroll
    for (int c = 0; c < 4; ++c) {
      #pragma unroll
      for (int reg = 0; reg < 4; ++reg) {
        if (mrr[reg]) {
          const long row = rowbase + q * 4 + reg;
          g1h[row * D + ch * 64 + c * 16 + l15] = f2h(acc[c][reg]);
        }
      }
    }
  }
}

// ---- fused 3-hop kernel: one block (512 thr) per batch row ---------------------
// Mask-compacted (idxS, padded to x128). Hop 0 is PEELED: its phase 4 loads V
// fp32 (bit-exact) and captures an fp16 copy of the first 256 compacted rows
// into 32 VGPRs (kv0/kv1, statically indexed). Hops 1-2 phase 4 replay from
// registers (fp16 V — same numerics as the verified usevh baseline); rows
// beyond 256 keep the fp32 load path every hop.
__global__ __launch_bounds__(512, 4) void hops_kernel(
    const float* __restrict__ e1, const int* __restrict__ mask,
    const float* __restrict__ value, const unsigned short* __restrict__ g1h,
    const float* __restrict__ Wlin, const float* __restrict__ blin,
    const float* __restrict__ Watt, const float* __restrict__ Wv,
    const float* __restrict__ c3, float* __restrict__ out) {
  __shared__ float uS[D], cS[D], ubS[D], opS[D];
  __shared__ float attS[NN];
  __shared__ float part[4][D];
  __shared__ float oscr[8][D];
  __shared__ float redA[8], redB[8];
  __shared__ int idxS[NN];
  __shared__ int redI[8];
  __shared__ int padRowS;
  const int b = blockIdx.x;
  const int t = threadIdx.x;
  const int wv = t >> 6, lane = t & 63;
  const int grp = t >> 4, l = t & 15, d0 = (t & 15) * 8;
  const long base = (long)b * NN * D;
  const int* mb = mask + b * NN;
  if (t < D) uS[t] = e1[b * D + t];
  // ---- compaction: list of unmasked row indices (order-preserving) ----
  const int myMask = mb[t];
  {
    const unsigned long long bal = __ballot(myMask != 0);
    const int lanePre = __popcll(bal & ((1ULL << lane) - 1ULL));
    if (lane == 0) redI[wv] = __popcll(bal);
    if (!myMask) padRowS = t;          // benign race: any masked row works
    __syncthreads();
    int wbase = 0, cnt = 0;
    #pragma unroll
    for (int w2 = 0; w2 < 8; ++w2) {
      const int c = redI[w2];
      if (w2 < wv) wbase += c;
      cnt += c;
    }
    if (myMask) idxS[wbase + lanePre] = t;
    const int cntPad = (cnt + 127) & ~127;
    __syncthreads();
    for (int i = cnt + t; i < cntPad; i += 512) idxS[i] = padRowS;
    redI[0] = cntPad >> 7;             // number of 128-row blocks (uniform rewrite)
    __syncthreads();
  }
  const int nb = redI[0];
  uint4 kv0[4], kv1[4];                // fp16 V capture (32 VGPR), set in hop 0

  // ---- shared phase bodies (lambdas, inlined) ----
  auto phases123 = [&]() {
    // phase 1: 4 roles x 128 threads: role0/1 = c halves, role2/3 = ub halves
    {
      const int d = t & 127, role = t >> 7;
      const float* W = (role < 2) ? (Watt + D * D) : Wlin;
      const int k0 = (role & 1) * 64;
      const float* Wp = W + k0 * D + d;
      float a = 0.f;
      #pragma unroll 8
      for (int k = 0; k < 64; ++k) a += uS[k0 + k] * Wp[k * D];
      part[role][d] = a;
    }
    __syncthreads();
    if (t < D) cS[t] = part[0][t] + part[1][t] + c3[b * D + t];
    else if (t < 2 * D) { const int d2 = t - D; ubS[d2] = lrelu(part[2][d2] + part[3][d2] + blin[d2]); }
    __syncthreads();
    // waves 0-1: masked-row att value partials -> redB[0], redB[1]
    if (t < 128) {
      float v = lrelu(cS[t]);
      #pragma unroll
      for (int off = 32; off > 0; off >>= 1) v += __shfl_xor(v, off, 64);
      if (lane == 0) redB[wv] = v;
    }
    // phase 2: att[n] = sum_d lrelu(g1[n,d] + c[d]) for UNMASKED rows only
    {
      float creg[8];
      #pragma unroll
      for (int j = 0; j < 8; ++j) creg[j] = cS[d0 + j];
      for (int ii = 0; ii < nb; ++ii) {
        int ns[4]; uint4 g[4];
        #pragma unroll
        for (int j2 = 0; j2 < 4; ++j2) ns[j2] = idxS[ii * 128 + j2 * 32 + grp];
        #pragma unroll
        for (int j2 = 0; j2 < 4; ++j2)
          g[j2] = *reinterpret_cast<const uint4*>(g1h + base + (long)ns[j2] * D + d0);
        #pragma unroll
        for (int j2 = 0; j2 < 4; ++j2) {
          const unsigned short* e = reinterpret_cast<const unsigned short*>(&g[j2]);
          float s = 0.f;
          #pragma unroll
          for (int j = 0; j < 8; ++j) s += lrelu(h2f(e[j]) + creg[j]);
          #pragma unroll
          for (int off = 8; off > 0; off >>= 1) s += __shfl_xor(s, off, 16);
          if (l == 0) attS[ns[j2]] = s;
        }
      }
    }
    __syncthreads();
    // phase 3: masked softmax (max over ALL n incl. masked — matches ref); n = t
    {
      const float av = myMask ? attS[t] : (redB[0] + redB[1]);
      float m = av;
      #pragma unroll
      for (int off = 32; off > 0; off >>= 1) m = fmaxf(m, __shfl_xor(m, off, 64));
      if (lane == 0) redA[wv] = m;
      __syncthreads();
      m = redA[0];
      #pragma unroll
      for (int w2 = 1; w2 < 8; ++w2) m = fmaxf(m, redA[w2]);
      const float e0 = __expf(av - m) * (myMask ? 1.f : 0.f);
      float ss = e0;
      #pragma unroll
      for (int off = 32; off > 0; off >>= 1) ss += __shfl_xor(ss, off, 64);
      if (lane == 0) redB[wv] = ss;
      __syncthreads();
      float s = 1e-5f;
      #pragma unroll
      for (int w2 = 0; w2 < 8; ++w2) s += redB[w2];
      attS[t] = e0 / s;
    }
    __syncthreads();
  };
  auto loadTail4 = [&](float (&acc8)[8]) {      // phase-4 load path for ii>=2
    for (int ii = 2; ii < nb; ++ii) {
      int ns[4]; float4 va[4], vb[4];
      #pragma unroll
      for (int j2 = 0; j2 < 4; ++j2) ns[j2] = idxS[ii * 128 + j2 * 32 + grp];
      #pragma unroll
      for (int j2 = 0; j2 < 4; ++j2) {
        const float* vp = value + base + (long)ns[j2] * D + d0;
        va[j2] = *reinterpret_cast<const float4*>(vp);
        vb[j2] = *reinterpret_cast<const float4*>(vp + 4);
      }
      #pragma unroll
      for (int j2 = 0; j2 < 4; ++j2) {
        const float p = attS[ns[j2]];
        acc8[0] += p * va[j2].x; acc8[1] += p * va[j2].y;
        acc8[2] += p * va[j2].z; acc8[3] += p * va[j2].w;
        acc8[4] += p * vb[j2].x; acc8[5] += p * vb[j2].y;
        acc8[6] += p * vb[j2].z; acc8[7] += p * vb[j2].w;
      }
    }
  };
  auto finishTail = [&](float (&acc8)[8]) {     // reduce + o@Wv + l2norm
    #pragma unroll
    for (int j = 0; j < 8; ++j) {
      acc8[j] += __shfl_xor(acc8[j], 16, 64);
      acc8[j] += __shfl_xor(acc8[j], 32, 64);
    }
    if (lane < 16) {
      #pragma unroll
      for (int j = 0; j < 8; ++j) oscr[wv][lane * 8 + j] = acc8[j];
    }
    __syncthreads();
    if (t < D) {
      float s = 0.f;
      #pragma unroll
      for (int w2 = 0; w2 < 8; ++w2) s += oscr[w2][t];
      opS[t] = s;
    }
    __syncthreads();
    // phase 5a: o = o_pre @ Wv, 4-way k-split
    {
      const int d = t & 127, role = t >> 7;
      const int k0 = role * 32;
      const float* Wp = Wv + k0 * D + d;
      float a = 0.f;
      #pragma unroll 8
      for (int k = 0; k < 32; ++k) a += opS[k0 + k] * Wp[k * D];
      part[role][d] = a;
    }
    __syncthreads();
    // phase 5b: u = l2norm(ub + o)
    {
      float un = 0.f, sq = 0.f;
      if (t < D) {
        un = ubS[t] + part[0][t] + part[1][t] + part[2][t] + part[3][t];
        sq = un * un;
      }
      #pragma unroll
      for (int off = 32; off > 0; off >>= 1) sq += __shfl_xor(sq, off, 64);
      if (lane == 0) redA[wv] = sq;
      __syncthreads();
      float ns2 = 0.f;
      #pragma unroll
      for (int w2 = 0; w2 < 8; ++w2) ns2 += redA[w2];
      const float norm = sqrtf(ns2);
      const float inv = (norm > 1e-12f) ? (1.f / norm) : 1e12f;
      if (t < D) uS[t] = un * inv;
    }
    __syncthreads();
  };

  // ---- hop 0 (peeled): fp32 V loads (bit-exact) + fp16 capture ----
  phases123();
  {
    float acc8[8];
    #pragma unroll
    for (int j = 0; j < 8; ++j) acc8[j] = 0.f;
    if (nb > 0) {
      float4 va[4], vb[4];
      #pragma unroll
      for (int j2 = 0; j2 < 4; ++j2) {
        const float* vp = value + base + (long)idxS[j2 * 32 + grp] * D + d0;
        va[j2] = *reinterpret_cast<const float4*>(vp);
        vb[j2] = *reinterpret_cast<const float4*>(vp + 4);
      }
      #pragma unroll
      for (int j2 = 0; j2 < 4; ++j2) {
        const float p = attS[idxS[j2 * 32 + grp]];
        acc8[0] += p * va[j2].x; acc8[1] += p * va[j2].y;
        acc8[2] += p * va[j2].z; acc8[3] += p * va[j2].w;
        acc8[4] += p * vb[j2].x; acc8[5] += p * vb[j2].y;
        acc8[6] += p * vb[j2].z; acc8[7] += p * vb[j2].w;
        kv0[j2].x = (unsigned)f2h(va[j2].x) | ((unsigned)f2h(va[j2].y) << 16);
        kv0[j2].y = (unsigned)f2h(va[j2].z) | ((unsigned)f2h(va[j2].w) << 16);
        kv0[j2].z = (unsigned)f2h(vb[j2].x) | ((unsigned)f2h(vb[j2].y) << 16);
        kv0[j2].w = (unsigned)f2h(vb[j2].z) | ((unsigned)f2h(vb[j2].w) << 16);
      }
    }
    if (nb > 1) {
      float4 va[4], vb[4];
      #pragma unroll
      for (int j2 = 0; j2 < 4; ++j2) {
        const float* vp = value + base + (long)idxS[128 + j2 * 32 + grp] * D + d0;
        va[j2] = *reinterpret_cast<const float4*>(vp);
        vb[j2] = *reinterpret_cast<const float4*>(vp + 4);
      }
      #pragma unroll
      for (int j2 = 0; j2 < 4; ++j2) {
        const float p = attS[idxS[128 + j2 * 32 + grp]];
        acc8[0] += p * va[j2].x; acc8[1] += p * va[j2].y;
        acc8[2] += p * va[j2].z; acc8[3] += p * va[j2].w;
        acc8[4] += p * vb[j2].x; acc8[5] += p * vb[j2].y;
        acc8[6] += p * vb[j2].z; acc8[7] += p * vb[j2].w;
        kv1[j2].x = (unsigned)f2h(va[j2].x) | ((unsigned)f2h(va[j2].y) << 16);
        kv1[j2].y = (unsigned)f2h(va[j2].z) | ((unsigned)f2h(va[j2].w) << 16);
        kv1[j2].z = (unsigned)f2h(vb[j2].x) | ((unsigned)f2h(vb[j2].y) << 16);
        kv1[j2].w = (unsigned)f2h(vb[j2].z) | ((unsigned)f2h(vb[j2].w) << 16);
      }
    }
    loadTail4(acc8);
    finishTail(acc8);
  }
  // ---- hops 1-2: register replay (fp16 V) ----
  for (int hop = 1; hop < 3; ++hop) {
    phases123();
    float acc8[8];
    #pragma unroll
    for (int j = 0; j < 8; ++j) acc8[j] = 0.f;
    if (nb > 0) {
      #pragma unroll
      for (int j2 = 0; j2 < 4; ++j2) {
        const float p = attS[idxS[j2 * 32 + grp]];
        acc8[0] += p * h2f((unsigned short)(kv0[j2].x & 0xffffu));
        acc8[1] += p * h2f((unsigned short)(kv0[j2].x >> 16));
        acc8[2] += p * h2f((unsigned short)(kv0[j2].y & 0xffffu));
        acc8[3] += p * h2f((unsigned short)(kv0[j2].y >> 16));
        acc8[4] += p * h2f((unsigned short)(kv0[j2].z & 0xffffu));
        acc8[5] += p * h2f((unsigned short)(kv0[j2].z >> 16));
        acc8[6] += p * h2f((unsigned short)(kv0[j2].w & 0xffffu));
        acc8[7] += p * h2f((unsigned short)(kv0[j2].w >> 16));
      }
    }
    if (nb > 1) {
      #pragma unroll
      for (int j2 = 0; j2 < 4; ++j2) {
        const float p = attS[idxS[128 + j2 * 32 + grp]];
        acc8[0] += p * h2f((unsigned short)(kv1[j2].x & 0xffffu));
        acc8[1] += p * h2f((unsigned short)(kv1[j2].x >> 16));
        acc8[2] += p * h2f((unsigned short)(kv1[j2].y & 0xffffu));
        acc8[3] += p * h2f((unsigned short)(kv1[j2].y >> 16));
        acc8[4] += p * h2f((unsigned short)(kv1[j2].z & 0xffffu));
        acc8[5] += p * h2f((unsigned short)(kv1[j2].z >> 16));
        acc8[6] += p * h2f((unsigned short)(kv1[j2].w & 0xffffu));
        acc8[7] += p * h2f((unsigned short)(kv1[j2].w >> 16));
      }
    }
    loadTail4(acc8);
    finishTail(acc8);
  }
  if (t < D) out[b * D + t] = uS[t];
}

extern "C" void kernel_launch(void* const* d_in, const int* in_sizes, int n_in,
                              void* d_out, int out_size, void* d_ws, size_t ws_size,
                              hipStream_t stream) {
  const float* e1   = (const float*)d_in[0];
  const float* rel  = (const float*)d_in[1];
  const float* key  = (const float*)d_in[2];
  const float* val  = (const float*)d_in[3];
  const int*   mask = (const int*)d_in[4];
  const float* Wk   = (const float*)d_in[5];
  const float* Wv   = (const float*)d_in[6];
  const float* Wlin = (const float*)d_in[7];
  const float* blin = (const float*)d_in[8];
  const float* Watt = (const float*)d_in[9];
  const float* batt = (const float*)d_in[10];
  float* out = (float*)d_out;

  char* ws = (char*)d_ws;
  unsigned short* WhF = (unsigned short*)ws;                   // 32 KB (fragment order)
  unsigned short* WlF = (unsigned short*)(ws + 32 * 1024);     // 32 KB (fragment order)
  float*          c3  = (float*)(ws + 64 * 1024);              // 256 KB
  unsigned short* g1h = (unsigned short*)(ws + 512 * 1024);    // 64 MiB fp16

  prep_kernel<<<D + BB, 256, 0, stream>>>(Wk, Watt, batt, rel, WhF, WlF, c3);
  gemm_g1_kernel<<<2048, 256, 0, stream>>>(key, mask, WhF, WlF, g1h);
  hops_kernel<<<BB, 512, 0, stream>>>(e1, mask, val, g1h, Wlin, blin, Watt, Wv, c3, out);
}